// Round 5
// baseline (55.662 us; speedup 1.0000x reference)
//
#include <hip/hip_runtime.h>
#include <stdint.h>

#define NB    1024
#define IL    4096
#define NOUT  4096
#define FI    128
#define BTILE 8      // batches per block (bf16, packed 2/dword -> 16B per input row)
#define OSPLIT 4
#define OTILE (NOUT / OSPLIT)   // 1024 outputs per block

// round-to-nearest-even bf16, returned in the HIGH 16 bits (low 16 zeroed)
__device__ __forceinline__ uint32_t rne_bf16_hi(float x) {
  uint32_t u = __float_as_uint(x);
  u += 0x7FFFu + ((u >> 16) & 1u);
  return u & 0xFFFF0000u;
}

// prep: pack[o*FI+f] = (bf16(w[o,f]) << 16) | idx[o,f]   (idx < 4096 fits u16)
__global__ __launch_bounds__(256)
void pack_kernel(const int* __restrict__ idx, const float* __restrict__ w,
                 uint32_t* __restrict__ pack) {
  int i = blockIdx.x * 256 + threadIdx.x;
  pack[i] = rne_bf16_hi(w[i]) | ((uint32_t)idx[i] & 0xFFFFu);
}

template<bool PACKED>
__global__ __launch_bounds__(1024)
void lincond_kernel(const float* __restrict__ input,
                    const uint32_t* __restrict__ pack,
                    const int*  __restrict__ idxs,
                    const float* __restrict__ wgt,
                    const float* __restrict__ bias,
                    float* __restrict__ out) {
  // LDS tile: row i (0..4095) = 4 dwords; dword d packs batches (2d: lo16, 2d+1: hi16) as bf16
  __shared__ uint32_t lds[IL * (BTILE / 2)];   // 64 KB
  const int bid   = blockIdx.x;
  const int b0    = (bid >> 2) * BTILE;
  const int obase = (bid & 3) * OTILE;
  const int tid   = threadIdx.x;

  // stage 8 input rows -> bf16-pair LDS (coalesced dword reads, e = d*4096 + i)
  #pragma unroll
  for (int rep = 0; rep < 16; ++rep) {
    int e = rep * 1024 + tid;
    int d = e >> 12;          // 0..3 (batch pair)
    int i = e & (IL - 1);     // 0..4095
    float x0 = input[(size_t)(b0 + 2 * d)     * IL + i];
    float x1 = input[(size_t)(b0 + 2 * d + 1) * IL + i];
    lds[i * 4 + d] = rne_bf16_hi(x1) | (rne_bf16_hi(x0) >> 16);
  }
  __syncthreads();

  const int o = obase + tid;                 // one output per thread
  const uint4* rows = reinterpret_cast<const uint4*>(lds);
  float acc[8] = {0.f,0.f,0.f,0.f,0.f,0.f,0.f,0.f};

#define GBODY(IDXV, WV) {                                         \
    uint4 g = rows[(IDXV)];                                       \
    float wv = (WV);                                              \
    acc[0] = fmaf(wv, __uint_as_float(g.x << 16),         acc[0]);\
    acc[1] = fmaf(wv, __uint_as_float(g.x & 0xFFFF0000u), acc[1]);\
    acc[2] = fmaf(wv, __uint_as_float(g.y << 16),         acc[2]);\
    acc[3] = fmaf(wv, __uint_as_float(g.y & 0xFFFF0000u), acc[3]);\
    acc[4] = fmaf(wv, __uint_as_float(g.z << 16),         acc[4]);\
    acc[5] = fmaf(wv, __uint_as_float(g.z & 0xFFFF0000u), acc[5]);\
    acc[6] = fmaf(wv, __uint_as_float(g.w << 16),         acc[6]);\
    acc[7] = fmaf(wv, __uint_as_float(g.w & 0xFFFF0000u), acc[7]);}

#define PBODY(P) \
    GBODY((P.x & 0xFFFFu), __uint_as_float(P.x & 0xFFFF0000u)) \
    GBODY((P.y & 0xFFFFu), __uint_as_float(P.y & 0xFFFF0000u)) \
    GBODY((P.z & 0xFFFFu), __uint_as_float(P.z & 0xFFFF0000u)) \
    GBODY((P.w & 0xFFFFu), __uint_as_float(P.w & 0xFFFF0000u))

#define RBODY(IV, WV) \
    GBODY(((uint32_t)IV.x), WV.x) \
    GBODY(((uint32_t)IV.y), WV.y) \
    GBODY(((uint32_t)IV.z), WV.z) \
    GBODY(((uint32_t)IV.w), WV.w)

  if (PACKED) {
    const uint4* pw = reinterpret_cast<const uint4*>(pack) + (size_t)o * (FI / 4);
    #pragma unroll 2
    for (int j = 0; j < 8; ++j) {
      uint4 p0 = pw[j * 4 + 0];
      uint4 p1 = pw[j * 4 + 1];
      uint4 p2 = pw[j * 4 + 2];
      uint4 p3 = pw[j * 4 + 3];
      PBODY(p0) PBODY(p1) PBODY(p2) PBODY(p3)
    }
  } else {
    const int4*   ip = reinterpret_cast<const int4*>(idxs)  + (size_t)o * (FI / 4);
    const float4* wp = reinterpret_cast<const float4*>(wgt) + (size_t)o * (FI / 4);
    #pragma unroll 2
    for (int j = 0; j < 8; ++j) {
      int4   i0 = ip[j * 4 + 0], i1 = ip[j * 4 + 1], i2 = ip[j * 4 + 2], i3 = ip[j * 4 + 3];
      float4 w0 = wp[j * 4 + 0], w1 = wp[j * 4 + 1], w2 = wp[j * 4 + 2], w3 = wp[j * 4 + 3];
      RBODY(i0, w0) RBODY(i1, w1) RBODY(i2, w2) RBODY(i3, w3)
    }
  }

  const float bv = bias[o];
  #pragma unroll
  for (int k = 0; k < 8; ++k) {
    out[(size_t)(b0 + k) * NOUT + o] = acc[k] + bv;   // coalesced: lanes -> consecutive o
  }
}

extern "C" void kernel_launch(void* const* d_in, const int* in_sizes, int n_in,
                              void* d_out, int out_size, void* d_ws, size_t ws_size,
                              hipStream_t stream) {
  const float* input  = (const float*)d_in[0];
  const float* weight = (const float*)d_in[1];
  const float* bias   = (const float*)d_in[2];
  const int*   idxs   = (const int*)d_in[3];
  float*       out    = (float*)d_out;

  const size_t pack_bytes = (size_t)NOUT * FI * sizeof(uint32_t);  // 2 MB
  const int grid = (NB / BTILE) * OSPLIT;                          // 512 blocks

  if (ws_size >= pack_bytes) {
    uint32_t* pack = (uint32_t*)d_ws;
    pack_kernel<<<(NOUT * FI) / 256, 256, 0, stream>>>(idxs, weight, pack);
    lincond_kernel<true><<<grid, 1024, 0, stream>>>(input, pack, nullptr, nullptr, bias, out);
  } else {
    lincond_kernel<false><<<grid, 1024, 0, stream>>>(input, nullptr, idxs, weight, bias, out);
  }
}